// Round 4
// baseline (621.460 us; speedup 1.0000x reference)
//
#include <hip/hip_runtime.h>

// MultiScaleRetention. Inputs f32, output f32.
// B=2 T=2048 D=2048 H=8 DK=256 DV=512 C=64, N_chunks=32.
// R10 = R9 with the vsf LDS size bug fixed (vsf[2][512] -> vsf[2][1024];
// frag layout [kc2 2][quad 4][v 16][e 8] = 1024 u16/buffer; the kc2=1 band
// was overflowing into the other double-buffer slot -> absmax 0.256).
// R9: (1) retention: 512 blocks (vt=32 slices of 16 v) x 256 thr; S
// recurrence pure-register; St/vs LDS in MFMA-fragment layout ->
// conflict-free b128 reads; A/B register prefetch pipeline, 1 raw
// barrier/chunk. (2) out-GEMM gemm256v (256x128-tile 8-phase, VM4 ledger).
// ws (u16): P[2.1M] qk[16.8M] kT[8.4M] v[16.8M] o[16.8M] xb[8.4M] = 138.6MB.

typedef unsigned short u16;
typedef unsigned int u32;
typedef short bf16x8 __attribute__((ext_vector_type(8)));
typedef short s16x4 __attribute__((ext_vector_type(4)));
typedef float f32x4 __attribute__((ext_vector_type(4)));
typedef u32 u32x2 __attribute__((ext_vector_type(2)));

typedef __attribute__((address_space(3))) u32 lds_u32;
typedef __attribute__((address_space(1))) const u32 gbl_u32;

__device__ __forceinline__ float bf2f(u16 u) {
    union { u32 i; float f; } x; x.i = ((u32)u) << 16; return x.f;
}
__device__ __forceinline__ u16 f2bf(float f) {
    union { float f; u32 i; } x; x.f = f;
    u32 u = x.i;
    u += 0x7fffu + ((u >> 16) & 1u);   // RNE (finite only)
    return (u16)(u >> 16);
}
__device__ __forceinline__ f32x4 mfma16(bf16x8 a, bf16x8 b, f32x4 c) {
    return __builtin_amdgcn_mfma_f32_16x16x32_bf16(a, b, c, 0, 0, 0);
}
__device__ __forceinline__ void gload16(const u16* g, u16* lds) {
    __builtin_amdgcn_global_load_lds((gbl_u32*)(unsigned long long)g,
                                     (lds_u32*)(u32)(unsigned long long)lds, 16, 0, 0);
}

// ---------------------------------------------------------------------------
// f32 -> bf16 bulk convert. 8 elems/thread.
// ---------------------------------------------------------------------------
__global__ __launch_bounds__(256)
void cvt_bf16(const float* __restrict__ src, u16* __restrict__ dst)
{
    size_t i = ((size_t)blockIdx.x * 256 + threadIdx.x) * 8;
    f32x4 a = *(const f32x4*)(src + i);
    f32x4 b = *(const f32x4*)(src + i + 4);
    bf16x8 r;
#pragma unroll
    for (int j = 0; j < 4; j++) { r[j] = (short)f2bf(a[j]); r[j + 4] = (short)f2bf(b[j]); }
    *(bf16x8*)(dst + i) = r;
}

// ---------------------------------------------------------------------------
// 8-phase 256x256 NT GEMM: C[M][N] = A[M][K](bf16) @ B[N][K](bf16)^T, bf16 out.
// grid=(N/256, M/256), block=512 (8 waves: wm=wave>>2, wn=wave&3).
// Counted vmcnt(6) at phases 3/7 only. kc-band LDS staging (conflict-free).
// ---------------------------------------------------------------------------
__global__ __launch_bounds__(512, 2)
void gemm256(const u16* __restrict__ A, const u16* __restrict__ Bm,
             u16* __restrict__ C, int N, int K)
{
    __shared__ __align__(16) u16 As[2][2][256 * 32];
    __shared__ __align__(16) u16 Bs[2][2][256 * 32];
    const int tid = threadIdx.x;
    const int lane = tid & 63, wave = tid >> 6;
    const int quad = lane >> 4, l16 = lane & 15;
    const int wm = wave >> 2, wn = wave & 3;
    const int tn = blockIdx.x, tm = blockIdx.y;
    const int NTm1 = K / 64 - 1;
    const u16* Abase = A + (size_t)tm * 256 * K;
    const u16* Bbase = Bm + (size_t)tn * 256 * K;
    const int gr = tid >> 2;
    const int gc = (tid & 3) * 8;
    const int wv64 = wave * 64;

    f32x4 acc[8][4];
#pragma unroll
    for (int i = 0; i < 8; i++)
#pragma unroll
        for (int j = 0; j < 4; j++) acc[i][j] = (f32x4){0.f, 0.f, 0.f, 0.f};

    bf16x8 bq[8];
    bf16x8 af[4];

#define STAGE(arr, bf, kc, Gb, kt) do {                                         \
    int kt_ = (kt); kt_ = (kt_ > NTm1) ? NTm1 : kt_;                            \
    const u16* s_ = (Gb) + (size_t)gr * K + (size_t)kt_ * 64 + (kc) * 32 + gc;  \
    gload16(s_,                 &arr[bf][kc][wv64 * 8]);                        \
    gload16(s_ + (size_t)128 * K, &arr[bf][kc][(512 + wv64) * 8]);              \
} while (0)

#define LDA(bf, kc, mg) do {                                                    \
    _Pragma("unroll")                                                           \
    for (int j = 0; j < 4; j++)                                                 \
        af[j] = *(const bf16x8*)&As[bf][kc][(wm * 128 + (mg) * 64 + j * 16 + l16) * 32 + quad * 8]; \
} while (0)

#define LDB(bf) do {                                                            \
    _Pragma("unroll")                                                           \
    for (int kc_ = 0; kc_ < 2; kc_++)                                           \
        _Pragma("unroll")                                                       \
        for (int n_ = 0; n_ < 4; n_++)                                          \
            bq[kc_ * 4 + n_] = *(const bf16x8*)&Bs[bf][kc_][(wn * 64 + n_ * 16 + l16) * 32 + quad * 8]; \
} while (0)

#define MM16(kc, mg) do {                                                       \
    _Pragma("unroll")                                                           \
    for (int j = 0; j < 4; j++)                                                 \
        _Pragma("unroll")                                                       \
        for (int n_ = 0; n_ < 4; n_++)                                          \
            acc[(mg) * 4 + j][n_] = mfma16(af[j], bq[(kc) * 4 + n_], acc[(mg) * 4 + j][n_]); \
} while (0)

#define BAR   __builtin_amdgcn_s_barrier()
#define LGKM0 asm volatile("s_waitcnt lgkmcnt(0)" ::: "memory")
#define VM6   asm volatile("s_waitcnt vmcnt(6)" ::: "memory")
#define PRIO1 __builtin_amdgcn_s_setprio(1)
#define PRIO0 __builtin_amdgcn_s_setprio(0)

    STAGE(Bs, 0, 0, Bbase, 0);
    STAGE(Bs, 0, 1, Bbase, 0);
    STAGE(As, 0, 0, Abase, 0);
    STAGE(As, 0, 1, Abase, 0);
    asm volatile("s_waitcnt vmcnt(4)" ::: "memory");
    STAGE(Bs, 1, 0, Bbase, 1);
    STAGE(Bs, 1, 1, Bbase, 1);
    STAGE(As, 1, 0, Abase, 1);
    asm volatile("s_waitcnt vmcnt(6)" ::: "memory");
    BAR;

    const int NI = K / 128;
    for (int it = 0; it < NI; ++it) {
        const int t0 = 2 * it;
        LDB(0); LDA(0, 0, 0); STAGE(As, 1, 1, Abase, t0 + 1);
        BAR; LGKM0; PRIO1; MM16(0, 0); PRIO0; BAR;
        LDA(0, 0, 1); STAGE(Bs, 0, 0, Bbase, t0 + 2);
        BAR; LGKM0; PRIO1; MM16(0, 1); PRIO0; BAR;
        LDA(0, 1, 0); STAGE(Bs, 0, 1, Bbase, t0 + 2);
        BAR; LGKM0; PRIO1; MM16(1, 0); PRIO0; BAR;
        LDA(0, 1, 1); STAGE(As, 0, 0, Abase, t0 + 2);
        BAR; LGKM0; PRIO1; MM16(1, 1); PRIO0; VM6; BAR;
        LDB(1); LDA(1, 0, 0); STAGE(As, 0, 1, Abase, t0 + 2);
        BAR; LGKM0; PRIO1; MM16(0, 0); PRIO0; BAR;
        LDA(1, 0, 1); STAGE(Bs, 1, 0, Bbase, t0 + 3);
        BAR; LGKM0; PRIO1; MM16(0, 1); PRIO0; BAR;
        LDA(1, 1, 0); STAGE(Bs, 1, 1, Bbase, t0 + 3);
        BAR; LGKM0; PRIO1; MM16(1, 0); PRIO0; BAR;
        LDA(1, 1, 1); STAGE(As, 1, 0, Abase, t0 + 3);
        BAR; LGKM0; PRIO1; MM16(1, 1); PRIO0; VM6; BAR;
    }
    asm volatile("s_waitcnt vmcnt(0)" ::: "memory");

    const int row0 = tm * 256 + wm * 128 + quad * 4;
    const int col0 = tn * 256 + wn * 64 + l16;
#pragma unroll
    for (int mt = 0; mt < 8; mt++)
#pragma unroll
        for (int nt = 0; nt < 4; nt++)
#pragma unroll
            for (int r = 0; r < 4; r++)
                C[(size_t)(row0 + mt * 16 + r) * N + col0 + nt * 16] = f2bf(acc[mt][nt][r]);

#undef STAGE
#undef LDA
#undef LDB
#undef MM16
}

// ---------------------------------------------------------------------------
// 8-phase 256x128 NT GEMM variant, f32 out (final projection, N=2048).
// grid=(N/128, M/256), block=512 (wm=wave>>2 in [0,2), wn=wave&3: 32 cols).
// A-band = 2 loads/thread, B-band = 1 -> 6 loads/K-tile; VM4 at ph3/ph7.
// ---------------------------------------------------------------------------
__global__ __launch_bounds__(512, 2)
void gemm256v(const u16* __restrict__ A, const u16* __restrict__ Bm,
              float* __restrict__ C, int N, int K)
{
    __shared__ __align__(16) u16 As[2][2][256 * 32];
    __shared__ __align__(16) u16 Bs[2][2][128 * 32];
    const int tid = threadIdx.x;
    const int lane = tid & 63, wave = tid >> 6;
    const int quad = lane >> 4, l16 = lane & 15;
    const int wm = wave >> 2, wn = wave & 3;
    const int tn = blockIdx.x, tm = blockIdx.y;
    const int NTm1 = K / 64 - 1;
    const u16* Abase = A + (size_t)tm * 256 * K;
    const u16* Bbase = Bm + (size_t)tn * 128 * K;
    const int gr = tid >> 2;
    const int gc = (tid & 3) * 8;
    const int wv64 = wave * 64;

    f32x4 acc[8][2];
#pragma unroll
    for (int i = 0; i < 8; i++)
#pragma unroll
        for (int j = 0; j < 2; j++) acc[i][j] = (f32x4){0.f, 0.f, 0.f, 0.f};

    bf16x8 bq[4];
    bf16x8 af[4];

#define STAGEA(bf, kc, kt) do {                                                 \
    int kt_ = (kt); kt_ = (kt_ > NTm1) ? NTm1 : kt_;                            \
    const u16* s_ = Abase + (size_t)gr * K + (size_t)kt_ * 64 + (kc) * 32 + gc; \
    gload16(s_,                   &As[bf][kc][wv64 * 8]);                       \
    gload16(s_ + (size_t)128 * K, &As[bf][kc][(512 + wv64) * 8]);               \
} while (0)

#define STAGEB(bf, kc, kt) do {                                                 \
    int kt_ = (kt); kt_ = (kt_ > NTm1) ? NTm1 : kt_;                            \
    const u16* s_ = Bbase + (size_t)gr * K + (size_t)kt_ * 64 + (kc) * 32 + gc; \
    gload16(s_, &Bs[bf][kc][wv64 * 8]);                                         \
} while (0)

#define LDAv(bf, kc, mg) do {                                                   \
    _Pragma("unroll")                                                           \
    for (int j = 0; j < 4; j++)                                                 \
        af[j] = *(const bf16x8*)&As[bf][kc][(wm * 128 + (mg) * 64 + j * 16 + l16) * 32 + quad * 8]; \
} while (0)

#define LDBv(bf) do {                                                           \
    _Pragma("unroll")                                                           \
    for (int kc_ = 0; kc_ < 2; kc_++)                                           \
        _Pragma("unroll")                                                       \
        for (int n_ = 0; n_ < 2; n_++)                                          \
            bq[kc_ * 2 + n_] = *(const bf16x8*)&Bs[bf][kc_][(wn * 32 + n_ * 16 + l16) * 32 + quad * 8]; \
} while (0)

#define MM8(kc, mg) do {                                                        \
    _Pragma("unroll")                                                           \
    for (int j = 0; j < 4; j++)                                                 \
        _Pragma("unroll")                                                       \
        for (int n_ = 0; n_ < 2; n_++)                                          \
            acc[(mg) * 4 + j][n_] = mfma16(af[j], bq[(kc) * 2 + n_], acc[(mg) * 4 + j][n_]); \
} while (0)

#define VM4 asm volatile("s_waitcnt vmcnt(4)" ::: "memory")

    // prologue: tile0 (6 loads) + tile1 partial (4) -> vmcnt(4) = tile0 done
    STAGEB(0, 0, 0); STAGEB(0, 1, 0); STAGEA(0, 0, 0); STAGEA(0, 1, 0);
    STAGEB(1, 0, 1); STAGEB(1, 1, 1); STAGEA(1, 0, 1);
    VM4;
    BAR;

    const int NI = K / 128;
    for (int it = 0; it < NI; ++it) {
        const int t0 = 2 * it;
        LDBv(0); LDAv(0, 0, 0); STAGEA(1, 1, t0 + 1);
        BAR; LGKM0; PRIO1; MM8(0, 0); PRIO0; BAR;
        LDAv(0, 0, 1); STAGEB(0, 0, t0 + 2);
        BAR; LGKM0; PRIO1; MM8(0, 1); PRIO0; BAR;
        LDAv(0, 1, 0); STAGEB(0, 1, t0 + 2);
        BAR; LGKM0; PRIO1; MM8(1, 0); PRIO0; BAR;
        LDAv(0, 1, 1); STAGEA(0, 0, t0 + 2);
        BAR; LGKM0; PRIO1; MM8(1, 1); PRIO0; VM4; BAR;
        LDBv(1); LDAv(1, 0, 0); STAGEA(0, 1, t0 + 2);
        BAR; LGKM0; PRIO1; MM8(0, 0); PRIO0; BAR;
        LDAv(1, 0, 1); STAGEB(1, 0, t0 + 3);
        BAR; LGKM0; PRIO1; MM8(0, 1); PRIO0; BAR;
        LDAv(1, 1, 0); STAGEB(1, 1, t0 + 3);
        BAR; LGKM0; PRIO1; MM8(1, 0); PRIO0; BAR;
        LDAv(1, 1, 1); STAGEA(1, 0, t0 + 3);
        BAR; LGKM0; PRIO1; MM8(1, 1); PRIO0; VM4; BAR;
    }
    asm volatile("s_waitcnt vmcnt(0)" ::: "memory");

    const int row0 = tm * 256 + wm * 128 + quad * 4;
    const int col0 = tn * 128 + wn * 32 + l16;
#pragma unroll
    for (int mt = 0; mt < 8; mt++)
#pragma unroll
        for (int nt = 0; nt < 2; nt++)
#pragma unroll
            for (int r = 0; r < 4; r++)
                C[(size_t)(row0 + mt * 16 + r) * N + col0 + nt * 16] = acc[mt][nt][r];

#undef STAGEA
#undef STAGEB
#undef LDAv
#undef LDBv
#undef MM8
#undef VM4
#undef BAR
#undef LGKM0
#undef VM6
#undef PRIO1
#undef PRIO0
}

// ---------------------------------------------------------------------------
// Fused rotary + scores + kT. grid = 512 (bx = n*16 + bh), block 256.
// q/k live in fused qk buffer [4096][4096] (q cols 0-2047, k cols 2048-4095).
// ---------------------------------------------------------------------------
__global__ __launch_bounds__(256, 2)
void rotary_scores(u16* __restrict__ q, const u16* __restrict__ k,
                   u16* __restrict__ kT, u16* __restrict__ P)
{
    __shared__ u16 qS[64 * 264];
    __shared__ u16 kS[64 * 264];
    const int tid = threadIdx.x;
    const int lane = tid & 63, wave = tid >> 6;
    const int quad = lane >> 4, l16 = lane & 15;
    const int bx = blockIdx.x;
    const int bh = bx & 15, n = bx >> 4;
    const int b = bh >> 3, h = bh & 7;
    const int t0 = n * 64;

    const int row = tid >> 2;
    const int j0 = (tid & 3) * 32;
    const size_t rowbase = (size_t)(b * 2048 + t0 + row) * 4096 + h * 256;
    const float tpos = (float)(t0 + row);
#pragma unroll
    for (int i = 0; i < 4; i++) {
        int j = j0 + i * 8;
        bf16x8 x1 = *(const bf16x8*)(q + rowbase + j);
        bf16x8 x2 = *(const bf16x8*)(q + rowbase + j + 128);
        bf16x8 y1 = *(const bf16x8*)(k + rowbase + j);
        bf16x8 y2 = *(const bf16x8*)(k + rowbase + j + 128);
        bf16x8 o1, o2, p1, p2;
#pragma unroll
        for (int e = 0; e < 8; e++) {
            float inv = expf((-9.210340371976184f / 128.f) * (float)(j + e));
            float ang = tpos * inv;
            float sv = sinf(ang), cv = cosf(ang);
            float a = bf2f((u16)x1[e]), bb = bf2f((u16)x2[e]);
            o1[e] = (short)f2bf((a * cv - bb * sv) * 0.0625f);
            o2[e] = (short)f2bf((bb * cv + a * sv) * 0.0625f);
            float e1 = bf2f((u16)y1[e]), e2 = bf2f((u16)y2[e]);
            p1[e] = (short)f2bf(e1 * cv - e2 * sv);
            p2[e] = (short)f2bf(e2 * cv + e1 * sv);
        }
        *(bf16x8*)(q + rowbase + j)       = o1;
        *(bf16x8*)(q + rowbase + j + 128) = o2;
        *(bf16x8*)(qS + row * 264 + j)       = o1;
        *(bf16x8*)(qS + row * 264 + j + 128) = o2;
        *(bf16x8*)(kS + row * 264 + j)       = p1;
        *(bf16x8*)(kS + row * 264 + j + 128) = p2;
    }
    __syncthreads();

    const float logb = logf(1.0f - exp2f(-5.0f - (float)h));
    f32x4 sc[4];
#pragma unroll
    for (int i = 0; i < 4; i++) sc[i] = (f32x4){0.f, 0.f, 0.f, 0.f};
#pragma unroll
    for (int kc = 0; kc < 8; kc++) {
        bf16x8 af = *(const bf16x8*)(qS + (wave * 16 + l16) * 264 + kc * 32 + quad * 8);
#pragma unroll
        for (int mt = 0; mt < 4; mt++) {
            bf16x8 bk = *(const bf16x8*)(kS + (mt * 16 + l16) * 264 + kc * 32 + quad * 8);
            sc[mt] = mfma16(af, bk, sc[mt]);
        }
    }
    u16* Pb = P + ((size_t)(bh * 32 + n)) * 64 * 64;
#pragma unroll
    for (int r = 0; r < 4; r++) {
        int cr = wave * 16 + quad * 4 + r;
        float rowe = __expf(logb * (float)(cr - 63));
#pragma unroll
        for (int mt = 0; mt < 4; mt++) {
            int m = mt * 16 + l16;
            float val = (cr >= m) ? sc[mt][r] * rowe : 0.0f;
            Pb[cr * 64 + m] = f2bf(val);
        }
    }

    const int d = tid;
    u16* dst = kT + ((size_t)(bh * 256 + d)) * 2048 + t0;
#pragma unroll
    for (int g8 = 0; g8 < 8; g8++) {
        bf16x8 w;
#pragma unroll
        for (int e = 0; e < 8; e++) w[e] = (short)kS[(g8 * 8 + e) * 264 + d];
        *(bf16x8*)(dst + g8 * 8) = w;
    }
}

// ---------------------------------------------------------------------------
// Retention scan. grid = 512 (bx = vt*16 + bh, vt in [0,32)), block 256.
// Wave = c-group (inter/PV rows) AND d-band (update, 64 d each).
// S recurrence in fp32 regs (Sacc[4 d-tiles], pure register chain).
// St/vs in LDS in MFMA B-frag layout [kc][quad][l16][8]: conflict-free b128.
// A/B register prefetch sets; 1 raw s_barrier + lgkmcnt(0) per chunk.
// Ledger: chunk n writes Stf[n&1], vsf[(n+1)&1]; reads Stf[(n+1)&1] (=S(n-1)),
// vsf[n&1]. Every write/read pair crosses exactly one barrier.
// ---------------------------------------------------------------------------
__global__ __launch_bounds__(256, 2)
void retention(const u16* __restrict__ Q, const u16* __restrict__ KT,
               const u16* __restrict__ V, const u16* __restrict__ P,
               u16* __restrict__ O)
{
    __shared__ __align__(16) u16 Stf[2][4096];  // [kc 8][quad 4][l16 16][e 8]
    __shared__ __align__(16) u16 vsf[2][1024];  // [kc2 2][quad 4][v 16][e 8]

    const int tid = threadIdx.x;
    const int lane = tid & 63, wave = tid >> 6;
    const int quad = lane >> 4, l16 = lane & 15;
    const int bx = blockIdx.x;
    const int bh = bx & 15, vt = bx >> 4;
    const int b = bh >> 3, h = bh & 7;

    const float logb = logf(1.0f - exp2f(-5.0f - (float)h));
    const float cdec = __expf(logb * 64.0f);
    float qdecr[4];
#pragma unroll
    for (int r = 0; r < 4; r++)
        qdecr[r] = __expf(logb * (float)(wave * 16 + quad * 4 + r + 1));
    const int w4 = wave * 4;
    const float kdv = __expf(logb * (float)(63 - lane));
    // vs frag write base: cell [kc2=lane>>5][qt=(lane>>3)&3][v=w4+j][e=lane&7]
    const int vwb = (((lane >> 5) * 4 + ((lane >> 3) & 3)) * 16 + w4) * 8 + (lane & 7);

    for (int i = tid; i < 4096; i += 256) { Stf[0][i] = 0; Stf[1][i] = 0; }

    const u16* Qp  = Q  + (size_t)(b * 2048 + wave * 16 + l16) * 4096 + h * 256 + quad * 8;
    const u16* KTp = KT + (size_t)(bh * 256 + wave * 64 + l16) * 2048 + quad * 8;
    const u16* Pp  = P  + ((size_t)(bh * 32) * 64 + wave * 16 + l16) * 64 + quad * 8;
    const u16* Vp  = V  + (size_t)(b * 2048 + lane) * 4096 + h * 512 + vt * 16 + w4;
    u16* Ob = O + (size_t)(b * 2048 + wave * 16 + quad * 4) * 4096 + h * 512 + vt * 16 + l16;

    f32x4 Sacc[4];
#pragma unroll
    for (int dt = 0; dt < 4; dt++) Sacc[dt] = (f32x4){0.f, 0.f, 0.f, 0.f};

    bf16x8 qfA[8], qfB[8], ktA[8], ktB[8], pfA[2], pfB[2];
    u32x2 vvA, vvB;

#define LOADSET(nn, qf, kt, pf, vvn, nv) do {                                   \
    const int nL = (nn), vL = (nv);                                             \
    _Pragma("unroll")                                                           \
    for (int kc = 0; kc < 8; kc++)                                              \
        qf[kc] = *(const bf16x8*)(Qp + (size_t)nL * (64 * 4096) + kc * 32);     \
    _Pragma("unroll")                                                           \
    for (int dt = 0; dt < 4; dt++)                                              \
        _Pragma("unroll")                                                       \
        for (int kc2 = 0; kc2 < 2; kc2++)                                       \
            kt[dt * 2 + kc2] = *(const bf16x8*)(KTp + dt * (16 * 2048)          \
                                  + (size_t)nL * 64 + kc2 * 32);                \
    _Pragma("unroll")                                                           \
    for (int kc2 = 0; kc2 < 2; kc2++)                                           \
        pf[kc2] = *(const bf16x8*)(Pp + (size_t)nL * (64 * 64) + kc2 * 32);     \
    vvn = *(const u32x2*)(Vp + (size_t)vL * (64 * 4096));                       \
} while (0)

#define STAGEVS(buf, vvC) do {                                                  \
    u16* vd = &vsf[buf][0];                                                     \
    u16 e0 = (u16)(vvC[0] & 0xffff), e1 = (u16)(vvC[0] >> 16);                  \
    u16 e2 = (u16)(vvC[1] & 0xffff), e3 = (u16)(vvC[1] >> 16);                  \
    vd[vwb + 0 * 8] = f2bf(bf2f(e0) * kdv);                                     \
    vd[vwb + 1 * 8] = f2bf(bf2f(e1) * kdv);                                     \
    vd[vwb + 2 * 8] = f2bf(bf2f(e2) * kdv);                                     \
    vd[vwb + 3 * 8] = f2bf(bf2f(e3) * kdv);                                     \
} while (0)

    // prologue: vs(0) staged; set A = chunk 0 operands + v(1)
    u32x2 vv0 = *(const u32x2*)(Vp);
    LOADSET(0, qfA, ktA, pfA, vvA, 1);
    STAGEVS(0, vv0);

#define CHUNK(nn, qfC, ktC, pfC, vvC, qfN, ktN, pfN, vvN) do {                  \
    const int nC = (nn);                                                        \
    const int nP = (nC + 1 < 32) ? nC + 1 : 31;                                 \
    const int nV = (nC + 2 < 32) ? nC + 2 : 31;                                 \
    LOADSET(nP, qfN, ktN, pfN, vvN, nV);       /* stays in flight */            \
    asm volatile("s_waitcnt lgkmcnt(0)" ::: "memory");                          \
    __builtin_amdgcn_s_barrier();                                               \
    __builtin_amdgcn_sched_barrier(0);                                          \
    STAGEVS((nC + 1) & 1, vvC);                /* vs(n+1) */                    \
    /* inter: o = q @ S(n-1), S(n-1) frags in Stf[(n+1)&1] */                   \
    f32x4 oacc = (f32x4){0.f, 0.f, 0.f, 0.f};                                   \
    _Pragma("unroll")                                                           \
    for (int kc = 0; kc < 8; kc++) {                                            \
        bf16x8 bs = *(const bf16x8*)&Stf[(nC + 1) & 1][(kc * 4 + quad) * 128 + l16 * 8]; \
        oacc = mfma16(qfC[kc], bs, oacc);                                       \
    }                                                                           \
    /* vs frags (shared by update and PV) */                                    \
    bf16x8 bv0 = *(const bf16x8*)&vsf[nC & 1][(0 * 4 + quad) * 128 + l16 * 8];  \
    bf16x8 bv1 = *(const bf16x8*)&vsf[nC & 1][(1 * 4 + quad) * 128 + l16 * 8];  \
    /* update: S = S*cdec + kT(d-band) @ vs */                                  \
    _Pragma("unroll")                                                           \
    for (int dt = 0; dt < 4; dt++)                                              \
        _Pragma("unroll")                                                       \
        for (int e = 0; e < 4; e++) Sacc[dt][e] *= cdec;                        \
    _Pragma("unroll")                                                           \
    for (int dt = 0; dt < 4; dt++) {                                            \
        Sacc[dt] = mfma16(ktC[dt * 2 + 0], bv0, Sacc[dt]);                      \
        Sacc[dt] = mfma16(ktC[dt * 2 + 1], bv1, Sacc[dt]);                      \
    }                                                                           \
    /* scale inter by q_dec, add PV */                                          \
    _Pragma("unroll")                                                           \
    for (int r = 0; r < 4; r++) oacc[r] *= qdecr[r];                            \
    oacc = mfma16(pfC[0], bv0, oacc);                                           \
    oacc = mfma16(pfC[1], bv1, oacc);                                           \
    _Pragma("unroll")                                                           \
    for (int r = 0; r < 4; r++)                                                 \
        Ob[(size_t)(nC * 64 + r) * 4096] = f2bf(oacc[r]);                       \
    /* St refresh: S(n) into Stf[n&1], frag layout */                           \
    _Pragma("unroll")                                                           \
    for (int dt = 0; dt < 4; dt++) {                                            \
        s16x4 w;                                                                \
        _Pragma("unroll")                                                       \
        for (int r = 0; r < 4; r++) w[r] = (short)f2bf(Sacc[dt][r]);            \
        const int kct = 2 * wave + (dt >> 1);                                   \
        const int qt  = (2 * dt + (quad >> 1)) & 3;                             \
        *(s16x4*)&Stf[nC & 1][(kct * 4 + qt) * 128 + l16 * 8 + 4 * (quad & 1)] = w; \
    }                                                                           \
} while (0)

    for (int m = 0; m < 16; m++) {
        CHUNK(2 * m,     qfA, ktA, pfA, vvA, qfB, ktB, pfB, vvB);
        CHUNK(2 * m + 1, qfB, ktB, pfB, vvB, qfA, ktA, pfA, vvA);
    }
#undef CHUNK
#undef STAGEVS
#undef LOADSET
}

// ---------------------------------------------------------------------------
// RMSNorm over DV=512 per (b,t,h) row, * g_norm_weight(f32), * silu(g).
// grid = 8192 (4 rows/block), block = 256 (1 wave/row).
// ---------------------------------------------------------------------------
__global__ __launch_bounds__(256)
void norm_gate(const u16* __restrict__ O, const u16* __restrict__ G,
               const float* __restrict__ gw, u16* __restrict__ ON)
{
    const int lane = threadIdx.x & 63;
    const size_t row = (size_t)blockIdx.x * 4 + (threadIdx.x >> 6);
    bf16x8 ov = *(const bf16x8*)(O + row * 512 + lane * 8);
    bf16x8 gv = *(const bf16x8*)(G + row * 512 + lane * 8);
    f32x4 w0 = *(const f32x4*)(gw + lane * 8);
    f32x4 w1 = *(const f32x4*)(gw + lane * 8 + 4);
    float of[8], gf[8];
    float ss = 0.f;
#pragma unroll
    for (int j = 0; j < 8; j++) {
        of[j] = bf2f((u16)ov[j]);
        gf[j] = bf2f((u16)gv[j]);
        ss += of[j] * of[j];
    }
#pragma unroll
    for (int off = 32; off > 0; off >>= 1) ss += __shfl_down(ss, off);
    ss = __shfl(ss, 0);
    const float rms = rsqrtf(ss * (1.0f / 512.0f) + 1e-5f);
    bf16x8 res;
#pragma unroll
    for (int j = 0; j < 8; j++) {
        float wj = (j < 4) ? w0[j] : w1[j - 4];
        float xn = of[j] * rms * wj;
        float sg = gf[j] / (1.f + __expf(-gf[j]));
        res[j] = (short)f2bf(xn * sg);
    }
    *(bf16x8*)(ON + row * 512 + lane * 8) = res;
}

// ---------------------------------------------------------------------------
extern "C" void kernel_launch(void* const* d_in, const int* in_sizes, int n_in,
                              void* d_out, int out_size, void* d_ws, size_t ws_size,
                              hipStream_t stream)
{
    const float* x  = (const float*)d_in[0];
    const float* Wq = (const float*)d_in[1];
    const float* Wk = (const float*)d_in[2];
    const float* Wv = (const float*)d_in[3];
    const float* Wg = (const float*)d_in[4];
    const float* Wo = (const float*)d_in[5];
    const float* gw = (const float*)d_in[6];
    float* out = (float*)d_out;

    const size_t M8 = (size_t)4096 * 2048;     // 8.4M u16
    u16* Pb = (u16*)d_ws;                      // 2.1M u16
    u16* qk = Pb + (size_t)16 * 32 * 64 * 64;  // fused q|k [4096][4096] (2*M8)
    u16* kT = qk + 2 * M8;                     // 8.4M
    u16* v  = kT + M8;                         // 16.8M
    u16* o  = v + 2 * M8;                      // 16.8M
    u16* xb = o + 2 * M8;                      // 8.4M
    u16* g  = qk;                              // alias qk (dead after retention)
    u16* on = v;                               // alias v (dead after retention)
    u16* wt = kT;                              // weight tmp (kT slot)

    dim3 blk(256, 1, 1), blk512(512, 1, 1);
    cvt_bf16<<<dim3(4096, 1, 1), blk, 0, stream>>>(x, xb);

    // fused q|k weight: Wq -> wt rows 0-2047, Wk -> rows 2048-4095
    cvt_bf16<<<dim3(2048, 1, 1), blk, 0, stream>>>(Wq, wt);
    cvt_bf16<<<dim3(2048, 1, 1), blk, 0, stream>>>(Wk, wt + (size_t)2048 * 2048);
    gemm256<<<dim3(16, 16, 1), blk512, 0, stream>>>(xb, wt, qk, 4096, 2048);
    cvt_bf16<<<dim3(4096, 1, 1), blk, 0, stream>>>(Wv, wt);
    gemm256<<<dim3(16, 16, 1), blk512, 0, stream>>>(xb, wt, v, 4096, 2048);

    rotary_scores<<<dim3(512, 1, 1), blk, 0, stream>>>(qk, qk + 2048, kT, Pb);
    retention<<<dim3(512, 1, 1), blk, 0, stream>>>(qk, kT, v, Pb, o);

    cvt_bf16<<<dim3(4096, 1, 1), blk, 0, stream>>>(Wg, kT);       // kT dead
    gemm256<<<dim3(16, 16, 1), blk512, 0, stream>>>(xb, kT, g, 4096, 2048);
    norm_gate<<<dim3(8192, 1, 1), blk, 0, stream>>>(o, g, gw, on);
    cvt_bf16<<<dim3(4096, 1, 1), blk, 0, stream>>>(Wo, kT);
    gemm256v<<<dim3(16, 16, 1), blk512, 0, stream>>>(on, kT, out, 2048, 4096);
}

// Round 5
// 593.929 us; speedup vs baseline: 1.0464x; 1.0464x over previous
//
#include <hip/hip_runtime.h>

// MultiScaleRetention. Inputs f32, output f32.
// B=2 T=2048 D=2048 H=8 DK=256 DV=512 C=64, N_chunks=32.
// R11: (1) retention reverted to the proven R8 structure (256 blocks x 512
// thr, 16 vt slices, A/B register prefetch, 1 raw barrier/chunk) with
// __launch_bounds__(512,1): grid=1 block/CU regardless, so raising the VGPR
// cap to 256 is free and lets BOTH prefetch sets stay resident (R8's VGPR=108
// forced spills -> loads serialized at use). R10's 512-block variant
// regressed (FETCH 35->51MB, occ 18%) and is dropped. (2) rotary_scores trig
// replaced by a precomputed cos/sin f32 table (rope_table kernel, 2MB,
// numerically identical) -> phase-1 VALU ~5x down. gemm256/gemm256v kept.
// ws (u16): P[2.1M] qk[16.8M] kT[8.4M] v[16.8M] o[16.8M] xb[8.4M]
//   + ropetab[2MB] = 140.6MB.

typedef unsigned short u16;
typedef unsigned int u32;
typedef short bf16x8 __attribute__((ext_vector_type(8)));
typedef short s16x4 __attribute__((ext_vector_type(4)));
typedef float f32x4 __attribute__((ext_vector_type(4)));
typedef u32 u32x2 __attribute__((ext_vector_type(2)));

typedef __attribute__((address_space(3))) u32 lds_u32;
typedef __attribute__((address_space(1))) const u32 gbl_u32;

__device__ __forceinline__ float bf2f(u16 u) {
    union { u32 i; float f; } x; x.i = ((u32)u) << 16; return x.f;
}
__device__ __forceinline__ u16 f2bf(float f) {
    union { float f; u32 i; } x; x.f = f;
    u32 u = x.i;
    u += 0x7fffu + ((u >> 16) & 1u);   // RNE (finite only)
    return (u16)(u >> 16);
}
__device__ __forceinline__ f32x4 mfma16(bf16x8 a, bf16x8 b, f32x4 c) {
    return __builtin_amdgcn_mfma_f32_16x16x32_bf16(a, b, c, 0, 0, 0);
}
__device__ __forceinline__ void gload16(const u16* g, u16* lds) {
    __builtin_amdgcn_global_load_lds((gbl_u32*)(unsigned long long)g,
                                     (lds_u32*)(u32)(unsigned long long)lds, 16, 0, 0);
}

// ---------------------------------------------------------------------------
// f32 -> bf16 bulk convert. 8 elems/thread.
// ---------------------------------------------------------------------------
__global__ __launch_bounds__(256)
void cvt_bf16(const float* __restrict__ src, u16* __restrict__ dst)
{
    size_t i = ((size_t)blockIdx.x * 256 + threadIdx.x) * 8;
    f32x4 a = *(const f32x4*)(src + i);
    f32x4 b = *(const f32x4*)(src + i + 4);
    bf16x8 r;
#pragma unroll
    for (int j = 0; j < 4; j++) { r[j] = (short)f2bf(a[j]); r[j + 4] = (short)f2bf(b[j]); }
    *(bf16x8*)(dst + i) = r;
}

// ---------------------------------------------------------------------------
// RoPE cos/sin table: tab[t*128 + jp] = {cos, sin}(t * base^(-jp/128)).
// 2048 x 128 entries, interleaved f32 pairs (2MB). One-time, ~5us.
// ---------------------------------------------------------------------------
__global__ __launch_bounds__(256)
void rope_table(float* __restrict__ tab)
{
    int idx = blockIdx.x * 256 + threadIdx.x;   // 262144 total
    int t = idx >> 7, jp = idx & 127;
    float inv = expf((-9.210340371976184f / 128.f) * (float)jp);
    float ang = (float)t * inv;
    tab[idx * 2 + 0] = cosf(ang);
    tab[idx * 2 + 1] = sinf(ang);
}

// ---------------------------------------------------------------------------
// 8-phase 256x256 NT GEMM: C[M][N] = A[M][K](bf16) @ B[N][K](bf16)^T, bf16 out.
// grid=(N/256, M/256), block=512 (8 waves: wm=wave>>2, wn=wave&3).
// Counted vmcnt(6) at phases 3/7 only. kc-band LDS staging (conflict-free).
// ---------------------------------------------------------------------------
__global__ __launch_bounds__(512, 2)
void gemm256(const u16* __restrict__ A, const u16* __restrict__ Bm,
             u16* __restrict__ C, int N, int K)
{
    __shared__ __align__(16) u16 As[2][2][256 * 32];
    __shared__ __align__(16) u16 Bs[2][2][256 * 32];
    const int tid = threadIdx.x;
    const int lane = tid & 63, wave = tid >> 6;
    const int quad = lane >> 4, l16 = lane & 15;
    const int wm = wave >> 2, wn = wave & 3;
    const int tn = blockIdx.x, tm = blockIdx.y;
    const int NTm1 = K / 64 - 1;
    const u16* Abase = A + (size_t)tm * 256 * K;
    const u16* Bbase = Bm + (size_t)tn * 256 * K;
    const int gr = tid >> 2;
    const int gc = (tid & 3) * 8;
    const int wv64 = wave * 64;

    f32x4 acc[8][4];
#pragma unroll
    for (int i = 0; i < 8; i++)
#pragma unroll
        for (int j = 0; j < 4; j++) acc[i][j] = (f32x4){0.f, 0.f, 0.f, 0.f};

    bf16x8 bq[8];
    bf16x8 af[4];

#define STAGE(arr, bf, kc, Gb, kt) do {                                         \
    int kt_ = (kt); kt_ = (kt_ > NTm1) ? NTm1 : kt_;                            \
    const u16* s_ = (Gb) + (size_t)gr * K + (size_t)kt_ * 64 + (kc) * 32 + gc;  \
    gload16(s_,                 &arr[bf][kc][wv64 * 8]);                        \
    gload16(s_ + (size_t)128 * K, &arr[bf][kc][(512 + wv64) * 8]);              \
} while (0)

#define LDA(bf, kc, mg) do {                                                    \
    _Pragma("unroll")                                                           \
    for (int j = 0; j < 4; j++)                                                 \
        af[j] = *(const bf16x8*)&As[bf][kc][(wm * 128 + (mg) * 64 + j * 16 + l16) * 32 + quad * 8]; \
} while (0)

#define LDB(bf) do {                                                            \
    _Pragma("unroll")                                                           \
    for (int kc_ = 0; kc_ < 2; kc_++)                                           \
        _Pragma("unroll")                                                       \
        for (int n_ = 0; n_ < 4; n_++)                                          \
            bq[kc_ * 4 + n_] = *(const bf16x8*)&Bs[bf][kc_][(wn * 64 + n_ * 16 + l16) * 32 + quad * 8]; \
} while (0)

#define MM16(kc, mg) do {                                                       \
    _Pragma("unroll")                                                           \
    for (int j = 0; j < 4; j++)                                                 \
        _Pragma("unroll")                                                       \
        for (int n_ = 0; n_ < 4; n_++)                                          \
            acc[(mg) * 4 + j][n_] = mfma16(af[j], bq[(kc) * 4 + n_], acc[(mg) * 4 + j][n_]); \
} while (0)

#define BAR   __builtin_amdgcn_s_barrier()
#define LGKM0 asm volatile("s_waitcnt lgkmcnt(0)" ::: "memory")
#define VM6   asm volatile("s_waitcnt vmcnt(6)" ::: "memory")
#define PRIO1 __builtin_amdgcn_s_setprio(1)
#define PRIO0 __builtin_amdgcn_s_setprio(0)

    STAGE(Bs, 0, 0, Bbase, 0);
    STAGE(Bs, 0, 1, Bbase, 0);
    STAGE(As, 0, 0, Abase, 0);
    STAGE(As, 0, 1, Abase, 0);
    asm volatile("s_waitcnt vmcnt(4)" ::: "memory");
    STAGE(Bs, 1, 0, Bbase, 1);
    STAGE(Bs, 1, 1, Bbase, 1);
    STAGE(As, 1, 0, Abase, 1);
    asm volatile("s_waitcnt vmcnt(6)" ::: "memory");
    BAR;

    const int NI = K / 128;
    for (int it = 0; it < NI; ++it) {
        const int t0 = 2 * it;
        LDB(0); LDA(0, 0, 0); STAGE(As, 1, 1, Abase, t0 + 1);
        BAR; LGKM0; PRIO1; MM16(0, 0); PRIO0; BAR;
        LDA(0, 0, 1); STAGE(Bs, 0, 0, Bbase, t0 + 2);
        BAR; LGKM0; PRIO1; MM16(0, 1); PRIO0; BAR;
        LDA(0, 1, 0); STAGE(Bs, 0, 1, Bbase, t0 + 2);
        BAR; LGKM0; PRIO1; MM16(1, 0); PRIO0; BAR;
        LDA(0, 1, 1); STAGE(As, 0, 0, Abase, t0 + 2);
        BAR; LGKM0; PRIO1; MM16(1, 1); PRIO0; VM6; BAR;
        LDB(1); LDA(1, 0, 0); STAGE(As, 0, 1, Abase, t0 + 2);
        BAR; LGKM0; PRIO1; MM16(0, 0); PRIO0; BAR;
        LDA(1, 0, 1); STAGE(Bs, 1, 0, Bbase, t0 + 3);
        BAR; LGKM0; PRIO1; MM16(0, 1); PRIO0; BAR;
        LDA(1, 1, 0); STAGE(Bs, 1, 1, Bbase, t0 + 3);
        BAR; LGKM0; PRIO1; MM16(1, 0); PRIO0; BAR;
        LDA(1, 1, 1); STAGE(As, 1, 0, Abase, t0 + 3);
        BAR; LGKM0; PRIO1; MM16(1, 1); PRIO0; VM6; BAR;
    }
    asm volatile("s_waitcnt vmcnt(0)" ::: "memory");

    const int row0 = tm * 256 + wm * 128 + quad * 4;
    const int col0 = tn * 256 + wn * 64 + l16;
#pragma unroll
    for (int mt = 0; mt < 8; mt++)
#pragma unroll
        for (int nt = 0; nt < 4; nt++)
#pragma unroll
            for (int r = 0; r < 4; r++)
                C[(size_t)(row0 + mt * 16 + r) * N + col0 + nt * 16] = f2bf(acc[mt][nt][r]);

#undef STAGE
#undef LDA
#undef LDB
#undef MM16
}

// ---------------------------------------------------------------------------
// 8-phase 256x128 NT GEMM variant, f32 out (final projection, N=2048).
// grid=(N/128, M/256), block=512 (wm=wave>>2 in [0,2), wn=wave&3: 32 cols).
// A-band = 2 loads/thread, B-band = 1 -> 6 loads/K-tile; VM4 at ph3/ph7.
// ---------------------------------------------------------------------------
__global__ __launch_bounds__(512, 2)
void gemm256v(const u16* __restrict__ A, const u16* __restrict__ Bm,
              float* __restrict__ C, int N, int K)
{
    __shared__ __align__(16) u16 As[2][2][256 * 32];
    __shared__ __align__(16) u16 Bs[2][2][128 * 32];
    const int tid = threadIdx.x;
    const int lane = tid & 63, wave = tid >> 6;
    const int quad = lane >> 4, l16 = lane & 15;
    const int wm = wave >> 2, wn = wave & 3;
    const int tn = blockIdx.x, tm = blockIdx.y;
    const int NTm1 = K / 64 - 1;
    const u16* Abase = A + (size_t)tm * 256 * K;
    const u16* Bbase = Bm + (size_t)tn * 128 * K;
    const int gr = tid >> 2;
    const int gc = (tid & 3) * 8;
    const int wv64 = wave * 64;

    f32x4 acc[8][2];
#pragma unroll
    for (int i = 0; i < 8; i++)
#pragma unroll
        for (int j = 0; j < 2; j++) acc[i][j] = (f32x4){0.f, 0.f, 0.f, 0.f};

    bf16x8 bq[4];
    bf16x8 af[4];

#define STAGEA(bf, kc, kt) do {                                                 \
    int kt_ = (kt); kt_ = (kt_ > NTm1) ? NTm1 : kt_;                            \
    const u16* s_ = Abase + (size_t)gr * K + (size_t)kt_ * 64 + (kc) * 32 + gc; \
    gload16(s_,                   &As[bf][kc][wv64 * 8]);                       \
    gload16(s_ + (size_t)128 * K, &As[bf][kc][(512 + wv64) * 8]);               \
} while (0)

#define STAGEB(bf, kc, kt) do {                                                 \
    int kt_ = (kt); kt_ = (kt_ > NTm1) ? NTm1 : kt_;                            \
    const u16* s_ = Bbase + (size_t)gr * K + (size_t)kt_ * 64 + (kc) * 32 + gc; \
    gload16(s_, &Bs[bf][kc][wv64 * 8]);                                         \
} while (0)

#define LDAv(bf, kc, mg) do {                                                   \
    _Pragma("unroll")                                                           \
    for (int j = 0; j < 4; j++)                                                 \
        af[j] = *(const bf16x8*)&As[bf][kc][(wm * 128 + (mg) * 64 + j * 16 + l16) * 32 + quad * 8]; \
} while (0)

#define LDBv(bf) do {                                                           \
    _Pragma("unroll")                                                           \
    for (int kc_ = 0; kc_ < 2; kc_++)                                           \
        _Pragma("unroll")                                                       \
        for (int n_ = 0; n_ < 2; n_++)                                          \
            bq[kc_ * 2 + n_] = *(const bf16x8*)&Bs[bf][kc_][(wn * 32 + n_ * 16 + l16) * 32 + quad * 8]; \
} while (0)

#define MM8(kc, mg) do {                                                        \
    _Pragma("unroll")                                                           \
    for (int j = 0; j < 4; j++)                                                 \
        _Pragma("unroll")                                                       \
        for (int n_ = 0; n_ < 2; n_++)                                          \
            acc[(mg) * 4 + j][n_] = mfma16(af[j], bq[(kc) * 2 + n_], acc[(mg) * 4 + j][n_]); \
} while (0)

#define VM4 asm volatile("s_waitcnt vmcnt(4)" ::: "memory")

    // prologue: tile0 (6 loads) + tile1 partial (4) -> vmcnt(4) = tile0 done
    STAGEB(0, 0, 0); STAGEB(0, 1, 0); STAGEA(0, 0, 0); STAGEA(0, 1, 0);
    STAGEB(1, 0, 1); STAGEB(1, 1, 1); STAGEA(1, 0, 1);
    VM4;
    BAR;

    const int NI = K / 128;
    for (int it = 0; it < NI; ++it) {
        const int t0 = 2 * it;
        LDBv(0); LDAv(0, 0, 0); STAGEA(1, 1, t0 + 1);
        BAR; LGKM0; PRIO1; MM8(0, 0); PRIO0; BAR;
        LDAv(0, 0, 1); STAGEB(0, 0, t0 + 2);
        BAR; LGKM0; PRIO1; MM8(0, 1); PRIO0; BAR;
        LDAv(0, 1, 0); STAGEB(0, 1, t0 + 2);
        BAR; LGKM0; PRIO1; MM8(1, 0); PRIO0; BAR;
        LDAv(0, 1, 1); STAGEA(0, 0, t0 + 2);
        BAR; LGKM0; PRIO1; MM8(1, 1); PRIO0; VM4; BAR;
        LDBv(1); LDAv(1, 0, 0); STAGEA(0, 1, t0 + 2);
        BAR; LGKM0; PRIO1; MM8(0, 0); PRIO0; BAR;
        LDAv(1, 0, 1); STAGEB(1, 0, t0 + 3);
        BAR; LGKM0; PRIO1; MM8(0, 1); PRIO0; BAR;
        LDAv(1, 1, 0); STAGEB(1, 1, t0 + 3);
        BAR; LGKM0; PRIO1; MM8(1, 0); PRIO0; BAR;
        LDAv(1, 1, 1); STAGEA(1, 0, t0 + 3);
        BAR; LGKM0; PRIO1; MM8(1, 1); PRIO0; VM4; BAR;
    }
    asm volatile("s_waitcnt vmcnt(0)" ::: "memory");

    const int row0 = tm * 256 + wm * 128 + quad * 4;
    const int col0 = tn * 128 + wn * 32 + l16;
#pragma unroll
    for (int mt = 0; mt < 8; mt++)
#pragma unroll
        for (int nt = 0; nt < 2; nt++)
#pragma unroll
            for (int r = 0; r < 4; r++)
                C[(size_t)(row0 + mt * 16 + r) * N + col0 + nt * 16] = acc[mt][nt][r];

#undef STAGEA
#undef STAGEB
#undef LDAv
#undef LDBv
#undef MM8
#undef VM4
#undef BAR
#undef LGKM0
#undef VM6
#undef PRIO1
#undef PRIO0
}

// ---------------------------------------------------------------------------
// Fused rotary + scores + kT. grid = 512 (bx = n*16 + bh), block 256.
// q/k live in fused qk buffer [4096][4096] (q cols 0-2047, k cols 2048-4095).
// cos/sin from precomputed f32 table (rope_table).
// ---------------------------------------------------------------------------
__global__ __launch_bounds__(256, 2)
void rotary_scores(u16* __restrict__ q, const u16* __restrict__ k,
                   u16* __restrict__ kT, u16* __restrict__ P,
                   const float* __restrict__ tab)
{
    __shared__ u16 qS[64 * 264];
    __shared__ u16 kS[64 * 264];
    const int tid = threadIdx.x;
    const int lane = tid & 63, wave = tid >> 6;
    const int quad = lane >> 4, l16 = lane & 15;
    const int bx = blockIdx.x;
    const int bh = bx & 15, n = bx >> 4;
    const int b = bh >> 3, h = bh & 7;
    const int t0 = n * 64;

    const int row = tid >> 2;
    const int j0 = (tid & 3) * 32;
    const size_t rowbase = (size_t)(b * 2048 + t0 + row) * 4096 + h * 256;
    const float* tb = tab + (size_t)(t0 + row) * 256;   // 128 entries x {c,s}
#pragma unroll
    for (int i = 0; i < 4; i++) {
        int j = j0 + i * 8;
        bf16x8 x1 = *(const bf16x8*)(q + rowbase + j);
        bf16x8 x2 = *(const bf16x8*)(q + rowbase + j + 128);
        bf16x8 y1 = *(const bf16x8*)(k + rowbase + j);
        bf16x8 y2 = *(const bf16x8*)(k + rowbase + j + 128);
        f32x4 tv0 = *(const f32x4*)(tb + 2 * j);
        f32x4 tv1 = *(const f32x4*)(tb + 2 * j + 4);
        f32x4 tv2 = *(const f32x4*)(tb + 2 * j + 8);
        f32x4 tv3 = *(const f32x4*)(tb + 2 * j + 12);
        float cv_[8] = {tv0[0], tv0[2], tv1[0], tv1[2], tv2[0], tv2[2], tv3[0], tv3[2]};
        float sv_[8] = {tv0[1], tv0[3], tv1[1], tv1[3], tv2[1], tv2[3], tv3[1], tv3[3]};
        bf16x8 o1, o2, p1, p2;
#pragma unroll
        for (int e = 0; e < 8; e++) {
            float cv = cv_[e], sv = sv_[e];
            float a = bf2f((u16)x1[e]), bb = bf2f((u16)x2[e]);
            o1[e] = (short)f2bf((a * cv - bb * sv) * 0.0625f);
            o2[e] = (short)f2bf((bb * cv + a * sv) * 0.0625f);
            float e1 = bf2f((u16)y1[e]), e2 = bf2f((u16)y2[e]);
            p1[e] = (short)f2bf(e1 * cv - e2 * sv);
            p2[e] = (short)f2bf(e2 * cv + e1 * sv);
        }
        *(bf16x8*)(q + rowbase + j)       = o1;
        *(bf16x8*)(q + rowbase + j + 128) = o2;
        *(bf16x8*)(qS + row * 264 + j)       = o1;
        *(bf16x8*)(qS + row * 264 + j + 128) = o2;
        *(bf16x8*)(kS + row * 264 + j)       = p1;
        *(bf16x8*)(kS + row * 264 + j + 128) = p2;
    }
    __syncthreads();

    const float logb = logf(1.0f - exp2f(-5.0f - (float)h));
    f32x4 sc[4];
#pragma unroll
    for (int i = 0; i < 4; i++) sc[i] = (f32x4){0.f, 0.f, 0.f, 0.f};
#pragma unroll
    for (int kc = 0; kc < 8; kc++) {
        bf16x8 af = *(const bf16x8*)(qS + (wave * 16 + l16) * 264 + kc * 32 + quad * 8);
#pragma unroll
        for (int mt = 0; mt < 4; mt++) {
            bf16x8 bk = *(const bf16x8*)(kS + (mt * 16 + l16) * 264 + kc * 32 + quad * 8);
            sc[mt] = mfma16(af, bk, sc[mt]);
        }
    }
    u16* Pb = P + ((size_t)(bh * 32 + n)) * 64 * 64;
#pragma unroll
    for (int r = 0; r < 4; r++) {
        int cr = wave * 16 + quad * 4 + r;
        float rowe = __expf(logb * (float)(cr - 63));
#pragma unroll
        for (int mt = 0; mt < 4; mt++) {
            int m = mt * 16 + l16;
            float val = (cr >= m) ? sc[mt][r] * rowe : 0.0f;
            Pb[cr * 64 + m] = f2bf(val);
        }
    }

    const int d = tid;
    u16* dst = kT + ((size_t)(bh * 256 + d)) * 2048 + t0;
#pragma unroll
    for (int g8 = 0; g8 < 8; g8++) {
        bf16x8 w;
#pragma unroll
        for (int e = 0; e < 8; e++) w[e] = (short)kS[(g8 * 8 + e) * 264 + d];
        *(bf16x8*)(dst + g8 * 8) = w;
    }
}

// ---------------------------------------------------------------------------
// Retention scan (R8 structure, proven): grid = 256 (bx = vt*16 + bh),
// block 512 (8 waves). vt = 32-wide DV slice. cgrp=wave>>1, vhalf=wave&1,
// d-band wave*32. S in fp32 regs; bf16 LDS mirrors St[2][32][264],
// vsT[2][32][72] (double-buffered). A/B register prefetch sets; 1 raw
// s_barrier + lgkmcnt(0) per chunk (prefetch stays in flight).
// __launch_bounds__(512,1): grid=1 block/CU anyway, so the raised VGPR cap
// (<=256) is free and lets both prefetch sets stay register-resident.
// Ledger: chunk n writes St[n&1], vsT[(n+1)&1]; reads St[(n+1)&1] (=S(n-1)),
// vsT[n&1]. Every write/read pair crosses exactly one barrier.
// ---------------------------------------------------------------------------
__global__ __launch_bounds__(512, 1)
void retention(const u16* __restrict__ Q, const u16* __restrict__ KT,
               const u16* __restrict__ V, const u16* __restrict__ P,
               u16* __restrict__ O)
{
    __shared__ u16 St[2][32 * 264];
    __shared__ u16 vsT[2][32 * 72];

    const int tid = threadIdx.x;
    const int lane = tid & 63, wave = tid >> 6;
    const int quad = lane >> 4, l16 = lane & 15;
    const int bx = blockIdx.x;
    const int bh = bx & 15, vt = bx >> 4;
    const int b = bh >> 3, h = bh & 7;
    const int cgrp = wave >> 1, vhalf = wave & 1;

    const float logb = logf(1.0f - exp2f(-5.0f - (float)h));
    const float cdec = __expf(logb * 64.0f);

    int cr[4];
    float qdecr[4];
#pragma unroll
    for (int r = 0; r < 4; r++) {
        cr[r] = cgrp * 16 + quad * 4 + r;
        qdecr[r] = __expf(logb * (float)(cr[r] + 1));
    }
    const int mv = tid >> 3;
    const int vc4 = (tid & 7) * 4;
    const float kdv = __expf(logb * (float)(63 - mv));

    for (int i = tid; i < 32 * 264; i += 512) { St[0][i] = 0; St[1][i] = 0; }

    // per-thread base pointers (chunk n adds n*stride)
    const u16* Qp  = Q  + (size_t)(b * 2048 + cgrp * 16 + l16) * 4096 + h * 256 + quad * 8;
    const u16* KTp = KT + (size_t)(bh * 256 + wave * 32 + l16) * 2048 + quad * 8;
    const u16* Pp  = P  + ((size_t)(bh * 32) * 64 + cgrp * 16 + l16) * 64 + quad * 8;
    const u16* Vp  = V  + (size_t)(b * 2048 + mv) * 4096 + h * 512 + vt * 32 + vc4;

    f32x4 Sacc[2][2];
#pragma unroll
    for (int dt = 0; dt < 2; dt++)
#pragma unroll
        for (int nt = 0; nt < 2; nt++) Sacc[dt][nt] = (f32x4){0.f, 0.f, 0.f, 0.f};

    bf16x8 qfA[8], qfB[8], ktA[4], ktB[4], pfA[2], pfB[2];
    u32x2 vvA, vvB;

#define LOADSET(nn, qf, kt, pf, vvn, nv) do {                                   \
    const int nL = (nn), vL = (nv);                                             \
    _Pragma("unroll")                                                           \
    for (int kc = 0; kc < 8; kc++)                                              \
        qf[kc] = *(const bf16x8*)(Qp + (size_t)nL * (64 * 4096) + kc * 32);     \
    _Pragma("unroll")                                                           \
    for (int dt = 0; dt < 2; dt++)                                              \
        _Pragma("unroll")                                                       \
        for (int kc2 = 0; kc2 < 2; kc2++)                                       \
            kt[dt * 2 + kc2] = *(const bf16x8*)(KTp + dt * (16 * 2048) + nL * 64 + kc2 * 32); \
    _Pragma("unroll")                                                           \
    for (int kc2 = 0; kc2 < 2; kc2++)                                           \
        pf[kc2] = *(const bf16x8*)(Pp + (size_t)nL * (64 * 64) + kc2 * 32);     \
    vvn = *(const u32x2*)(Vp + (size_t)vL * (64 * 4096));                       \
} while (0)

    // prologue: stage vsT[0] from v(0); set A = chunk 0 operands; vvA = v(1)
    u32x2 vv0 = *(const u32x2*)(Vp);
    LOADSET(0, qfA, ktA, pfA, vvA, 1);
    {
        u16 e0 = (u16)(vv0[0] & 0xffff), e1 = (u16)(vv0[0] >> 16);
        u16 e2 = (u16)(vv0[1] & 0xffff), e3 = (u16)(vv0[1] >> 16);
        vsT[0][(vc4 + 0) * 72 + mv] = f2bf(bf2f(e0) * kdv);
        vsT[0][(vc4 + 1) * 72 + mv] = f2bf(bf2f(e1) * kdv);
        vsT[0][(vc4 + 2) * 72 + mv] = f2bf(bf2f(e2) * kdv);
        vsT[0][(vc4 + 3) * 72 + mv] = f2bf(bf2f(e3) * kdv);
    }

#define CHUNK(nn, qfC, ktC, pfC, vvC, qfN, ktN, pfN, vvN) do {                  \
    const int nC = (nn);                                                        \
    const int nP = (nC + 1 < 32) ? nC + 1 : 31;                                 \
    const int nV = (nC + 2 < 32) ? nC + 2 : 31;                                 \
    LOADSET(nP, qfN, ktN, pfN, vvN, nV);       /* prefetch, stays in flight */  \
    asm volatile("s_waitcnt lgkmcnt(0)" ::: "memory");                          \
    __builtin_amdgcn_s_barrier();                                               \
    __builtin_amdgcn_sched_barrier(0);                                          \
    {   /* stage vsT[(n+1)&1] from vvC = v(n+1) */                              \
        u16* vd = &vsT[(nC + 1) & 1][0];                                        \
        u16 e0 = (u16)(vvC[0] & 0xffff), e1 = (u16)(vvC[0] >> 16);              \
        u16 e2 = (u16)(vvC[1] & 0xffff), e3 = (u16)(vvC[1] >> 16);              \
        vd[(vc4 + 0) * 72 + mv] = f2bf(bf2f(e0) * kdv);                         \
        vd[(vc4 + 1) * 72 + mv] = f2bf(bf2f(e1) * kdv);                         \
        vd[(vc4 + 2) * 72 + mv] = f2bf(bf2f(e2) * kdv);                         \
        vd[(vc4 + 3) * 72 + mv] = f2bf(bf2f(e3) * kdv);                         \
    }                                                                           \
    /* inter: o = q @ S(n-1); S(n-1) lives in St[(n+1)&1] */                    \
    f32x4 oacc = (f32x4){0.f, 0.f, 0.f, 0.f};                                   \
    _Pragma("unroll")                                                           \
    for (int kc = 0; kc < 8; kc++) {                                            \
        bf16x8 bs = *(const bf16x8*)(&St[(nC + 1) & 1][0]                       \
                     + (vhalf * 16 + l16) * 264 + kc * 32 + quad * 8);          \
        oacc = mfma16(qfC[kc], bs, oacc);                                       \
    }                                                                           \
    /* update: S = S*cdec + kT @ vs(n); vs(n) in vsT[n&1] */                    \
    _Pragma("unroll")                                                           \
    for (int dt = 0; dt < 2; dt++)                                              \
        _Pragma("unroll")                                                       \
        for (int nt = 0; nt < 2; nt++)                                          \
            _Pragma("unroll")                                                   \
            for (int e = 0; e < 4; e++) Sacc[dt][nt][e] *= cdec;                \
    _Pragma("unroll")                                                           \
    for (int kc2 = 0; kc2 < 2; kc2++) {                                         \
        bf16x8 bv0 = *(const bf16x8*)(&vsT[nC & 1][0] + l16 * 72 + kc2 * 32 + quad * 8);        \
        bf16x8 bv1 = *(const bf16x8*)(&vsT[nC & 1][0] + (16 + l16) * 72 + kc2 * 32 + quad * 8); \
        _Pragma("unroll")                                                       \
        for (int dt = 0; dt < 2; dt++) {                                        \
            Sacc[dt][0] = mfma16(ktC[dt * 2 + kc2], bv0, Sacc[dt][0]);          \
            Sacc[dt][1] = mfma16(ktC[dt * 2 + kc2], bv1, Sacc[dt][1]);          \
        }                                                                       \
    }                                                                           \
    /* scale inter by q_dec, add PV */                                          \
    _Pragma("unroll")                                                           \
    for (int r = 0; r < 4; r++) oacc[r] *= qdecr[r];                            \
    _Pragma("unroll")                                                           \
    for (int kc2 = 0; kc2 < 2; kc2++) {                                         \
        bf16x8 bv = *(const bf16x8*)(&vsT[nC & 1][0]                            \
                     + (vhalf * 16 + l16) * 72 + kc2 * 32 + quad * 8);          \
        oacc = mfma16(pfC[kc2], bv, oacc);                                      \
    }                                                                           \
    _Pragma("unroll")                                                           \
    for (int r = 0; r < 4; r++)                                                 \
        O[(size_t)(b * 2048 + nC * 64 + cr[r]) * 4096 + h * 512 + vt * 32       \
          + vhalf * 16 + l16] = f2bf(oacc[r]);                                  \
    /* St refresh: write S(n) into St[n&1] */                                   \
    _Pragma("unroll")                                                           \
    for (int dt = 0; dt < 2; dt++)                                              \
        _Pragma("unroll")                                                       \
        for (int nt = 0; nt < 2; nt++) {                                        \
            s16x4 w;                                                            \
            _Pragma("unroll")                                                   \
            for (int r = 0; r < 4; r++) w[r] = (short)f2bf(Sacc[dt][nt][r]);    \
            *(s16x4*)(&St[nC & 1][0] + (nt * 16 + l16) * 264 + wave * 32        \
                      + dt * 16 + quad * 4) = w;                                \
        }                                                                       \
} while (0)

    for (int m = 0; m < 16; m++) {
        CHUNK(2 * m,     qfA, ktA, pfA, vvA, qfB, ktB, pfB, vvB);
        CHUNK(2 * m + 1, qfB, ktB, pfB, vvB, qfA, ktA, pfA, vvA);
    }
#undef CHUNK
#undef LOADSET
}

// ---------------------------------------------------------------------------
// RMSNorm over DV=512 per (b,t,h) row, * g_norm_weight(f32), * silu(g).
// grid = 8192 (4 rows/block), block = 256 (1 wave/row).
// ---------------------------------------------------------------------------
__global__ __launch_bounds__(256)
void norm_gate(const u16* __restrict__ O, const u16* __restrict__ G,
               const float* __restrict__ gw, u16* __restrict__ ON)
{
    const int lane = threadIdx.x & 63;
    const size_t row = (size_t)blockIdx.x * 4 + (threadIdx.x >> 6);
    bf16x8 ov = *(const bf16x8*)(O + row * 512 + lane * 8);
    bf16x8 gv = *(const bf16x8*)(G + row * 512 + lane * 8);
    f32x4 w0 = *(const f32x4*)(gw + lane * 8);
    f32x4 w1 = *(const f32x4*)(gw + lane * 8 + 4);
    float of[8], gf[8];
    float ss = 0.f;
#pragma unroll
    for (int j = 0; j < 8; j++) {
        of[j] = bf2f((u16)ov[j]);
        gf[j] = bf2f((u16)gv[j]);
        ss += of[j] * of[j];
    }
#pragma unroll
    for (int off = 32; off > 0; off >>= 1) ss += __shfl_down(ss, off);
    ss = __shfl(ss, 0);
    const float rms = rsqrtf(ss * (1.0f / 512.0f) + 1e-5f);
    bf16x8 res;
#pragma unroll
    for (int j = 0; j < 8; j++) {
        float wj = (j < 4) ? w0[j] : w1[j - 4];
        float xn = of[j] * rms * wj;
        float sg = gf[j] / (1.f + __expf(-gf[j]));
        res[j] = (short)f2bf(xn * sg);
    }
    *(bf16x8*)(ON + row * 512 + lane * 8) = res;
}

// ---------------------------------------------------------------------------
extern "C" void kernel_launch(void* const* d_in, const int* in_sizes, int n_in,
                              void* d_out, int out_size, void* d_ws, size_t ws_size,
                              hipStream_t stream)
{
    const float* x  = (const float*)d_in[0];
    const float* Wq = (const float*)d_in[1];
    const float* Wk = (const float*)d_in[2];
    const float* Wv = (const float*)d_in[3];
    const float* Wg = (const float*)d_in[4];
    const float* Wo = (const float*)d_in[5];
    const float* gw = (const float*)d_in[6];
    float* out = (float*)d_out;

    const size_t M8 = (size_t)4096 * 2048;     // 8.4M u16
    u16* Pb = (u16*)d_ws;                      // 2.1M u16
    u16* qk = Pb + (size_t)16 * 32 * 64 * 64;  // fused q|k [4096][4096] (2*M8)
    u16* kT = qk + 2 * M8;                     // 8.4M
    u16* v  = kT + M8;                         // 16.8M
    u16* o  = v + 2 * M8;                      // 16.8M
    u16* xb = o + 2 * M8;                      // 8.4M
    float* tab = (float*)(xb + M8);            // 2MB rope table
    u16* g  = qk;                              // alias qk (dead after retention)
    u16* on = v;                               // alias v (dead after retention)
    u16* wt = kT;                              // weight tmp (kT slot)

    dim3 blk(256, 1, 1), blk512(512, 1, 1);
    rope_table<<<dim3(1024, 1, 1), blk, 0, stream>>>(tab);
    cvt_bf16<<<dim3(4096, 1, 1), blk, 0, stream>>>(x, xb);

    // fused q|k weight: Wq -> wt rows 0-2047, Wk -> rows 2048-4095
    cvt_bf16<<<dim3(2048, 1, 1), blk, 0, stream>>>(Wq, wt);
    cvt_bf16<<<dim3(2048, 1, 1), blk, 0, stream>>>(Wk, wt + (size_t)2048 * 2048);
    gemm256<<<dim3(16, 16, 1), blk512, 0, stream>>>(xb, wt, qk, 4096, 2048);
    cvt_bf16<<<dim3(4096, 1, 1), blk, 0, stream>>>(Wv, wt);
    gemm256<<<dim3(16, 16, 1), blk512, 0, stream>>>(xb, wt, v, 4096, 2048);

    rotary_scores<<<dim3(512, 1, 1), blk, 0, stream>>>(qk, qk + 2048, kT, Pb, tab);
    retention<<<dim3(256, 1, 1), blk512, 0, stream>>>(qk, kT, v, Pb, o);

    cvt_bf16<<<dim3(4096, 1, 1), blk, 0, stream>>>(Wg, kT);       // kT dead
    gemm256<<<dim3(16, 16, 1), blk512, 0, stream>>>(xb, kT, g, 4096, 2048);
    norm_gate<<<dim3(8192, 1, 1), blk, 0, stream>>>(o, g, gw, on);
    cvt_bf16<<<dim3(4096, 1, 1), blk, 0, stream>>>(Wo, kT);
    gemm256v<<<dim3(16, 16, 1), blk512, 0, stream>>>(on, kT, out, 2048, 4096);
}